// Round 1
// baseline (3646.246 us; speedup 1.0000x reference)
//
#include <hip/hip_runtime.h>
#include <hip/hip_bf16.h>
#include <cmath>

#define BB 2
#define SS 2048
#define DD 2048
#define HHN 16
#define DHH 128
#define FFF 8192
#define NFF (3*DD+FFF)   // 14336
#define MR (BB*SS)       // 4096
#define LNEPS 1e-6f

typedef __hip_bfloat16 bf16;
using bf16x8 = __attribute__((ext_vector_type(8))) __bf16;
using f32x4  = __attribute__((ext_vector_type(4))) float;

// ---------------- convert f32 -> bf16 (vectorized) ----------------
__global__ __launch_bounds__(256) void k_convert(const float* __restrict__ in,
                                                 bf16* __restrict__ out, int n4) {
  int i = blockIdx.x * 256 + threadIdx.x;
  if (i >= n4) return;
  float4 v = ((const float4*)in)[i];
  out[4*i+0] = __float2bfloat16(v.x);
  out[4*i+1] = __float2bfloat16(v.y);
  out[4*i+2] = __float2bfloat16(v.z);
  out[4*i+3] = __float2bfloat16(v.w);
}

// ---------------- transpose+convert: in (R x C) f32 -> out (C x R) bf16 ----------------
__global__ __launch_bounds__(256) void k_transpose(const float* __restrict__ in,
                                                   bf16* __restrict__ out, int R, int C) {
  __shared__ float tile[32][33];
  int c0 = blockIdx.x * 32, r0 = blockIdx.y * 32;
  int tx = threadIdx.x, ty = threadIdx.y;
  #pragma unroll
  for (int i = 0; i < 32; i += 8)
    tile[ty + i][tx] = in[(size_t)(r0 + ty + i) * C + (c0 + tx)];
  __syncthreads();
  #pragma unroll
  for (int i = 0; i < 32; i += 8)
    out[(size_t)(c0 + ty + i) * R + (r0 + tx)] = __float2bfloat16(tile[tx][ty + i]);
}

// ---------------- bf16 MFMA GEMM: C[MxN] = A[MxK] @ BT[NxK]^T + bias ----------------
// mode 0: C f32 = v ; mode 1: C bf16 = v ; mode 2: C f32 = addin + silu(v)
__global__ __launch_bounds__(256) void k_gemm_bt(const bf16* __restrict__ A,
                                                 const bf16* __restrict__ BT,
                                                 const float* __restrict__ bias,
                                                 void* __restrict__ Cout,
                                                 const float* __restrict__ addin,
                                                 int M, int N, int K, int mode) {
  constexpr int LDT = 40;  // bf16 pitch: 80B rows, 16B-aligned, 2-way-max bank alias (free)
  __shared__ __align__(16) bf16 As[64 * LDT];
  __shared__ __align__(16) bf16 Bs[64 * LDT];
  int tid = threadIdx.x;
  int wave = tid >> 6, lane = tid & 63;
  int wm = wave >> 1, wn = wave & 1;
  int l15 = lane & 15, l4 = lane >> 4;
  int m0 = blockIdx.y * 64, n0 = blockIdx.x * 64;
  int sr = tid >> 2;          // staging row 0..63
  int sc = (tid & 3) * 8;     // staging k-offset
  const bf16* Aptr = A + (size_t)(m0 + sr) * K + sc;
  const bf16* Bptr = BT + (size_t)(n0 + sr) * K + sc;

  f32x4 acc[2][2];
  #pragma unroll
  for (int i = 0; i < 2; i++)
    #pragma unroll
    for (int j = 0; j < 2; j++)
      acc[i][j] = f32x4{0.f, 0.f, 0.f, 0.f};

  for (int k0 = 0; k0 < K; k0 += 32) {
    __syncthreads();
    *reinterpret_cast<bf16x8*>(&As[sr * LDT + sc]) =
        *reinterpret_cast<const bf16x8*>(Aptr + k0);
    *reinterpret_cast<bf16x8*>(&Bs[sr * LDT + sc]) =
        *reinterpret_cast<const bf16x8*>(Bptr + k0);
    __syncthreads();
    bf16x8 a0 = *reinterpret_cast<const bf16x8*>(&As[(wm * 32 + l15) * LDT + l4 * 8]);
    bf16x8 a1 = *reinterpret_cast<const bf16x8*>(&As[(wm * 32 + 16 + l15) * LDT + l4 * 8]);
    bf16x8 b0 = *reinterpret_cast<const bf16x8*>(&Bs[(wn * 32 + l15) * LDT + l4 * 8]);
    bf16x8 b1 = *reinterpret_cast<const bf16x8*>(&Bs[(wn * 32 + 16 + l15) * LDT + l4 * 8]);
    acc[0][0] = __builtin_amdgcn_mfma_f32_16x16x32_bf16(a0, b0, acc[0][0], 0, 0, 0);
    acc[0][1] = __builtin_amdgcn_mfma_f32_16x16x32_bf16(a0, b1, acc[0][1], 0, 0, 0);
    acc[1][0] = __builtin_amdgcn_mfma_f32_16x16x32_bf16(a1, b0, acc[1][0], 0, 0, 0);
    acc[1][1] = __builtin_amdgcn_mfma_f32_16x16x32_bf16(a1, b1, acc[1][1], 0, 0, 0);
  }

  float* Cf = (float*)Cout;
  bf16* Cb = (bf16*)Cout;
  #pragma unroll
  for (int i = 0; i < 2; i++) {
    #pragma unroll
    for (int j = 0; j < 2; j++) {
      int mbase = m0 + wm * 32 + i * 16 + l4 * 4;
      int nn = n0 + wn * 32 + j * 16 + l15;
      float bv = bias[nn];
      #pragma unroll
      for (int rr = 0; rr < 4; rr++) {
        size_t idx = (size_t)(mbase + rr) * N + nn;
        float v = acc[i][j][rr] + bv;
        if (mode == 0) {
          Cf[idx] = v;
        } else if (mode == 1) {
          Cb[idx] = __float2bfloat16(v);
        } else {
          float sig = 1.f / (1.f + expf(-v));
          Cf[idx] = addin[idx] + v * sig;
        }
      }
    }
  }
}

// ---------------- RoPE in-place on q,k regions of fused (bf16) ----------------
// ref rotate_half has NO negation: rh[d]=x[d+64] (d<64), rh[d]=x[d-64] (d>=64)
__global__ __launch_bounds__(256) void k_rope(bf16* __restrict__ fused,
                                              const float* __restrict__ rope_w) {
  int row = blockIdx.x;
  int s = row & (SS - 1);
  const float* rw = rope_w + (size_t)s * DHH;
  const float scale = 0.08838834764831845f;  // 1/sqrt(128)
  for (int idx = threadIdx.x; idx < HHN * 64; idx += 256) {
    int h = idx >> 6, d = idx & 63;
    float c1 = cosf(rw[d]),      s1 = sinf(rw[d]);
    float c2 = cosf(rw[d + 64]), s2 = sinf(rw[d + 64]);
    bf16* q = fused + (size_t)row * NFF + h * DHH;
    bf16* k = q + DD;
    float q0 = __bfloat162float(q[d]), q1 = __bfloat162float(q[d + 64]);
    q[d]      = __float2bfloat16((q0 * c1 + q1 * s1) * scale);
    q[d + 64] = __float2bfloat16((q1 * c2 + q0 * s2) * scale);
    float k0 = __bfloat162float(k[d]), k1 = __bfloat162float(k[d + 64]);
    k[d]      = __float2bfloat16(k0 * c1 + k1 * s1);
    k[d + 64] = __float2bfloat16(k1 * c2 + k0 * s2);
  }
}

// ---------------- causal flash attention (fp32 compute, bf16 I/O) ----------------
// grid: (S/64, B*H). 256 threads. thread -> (row r=tid>>2 of 64, quad=tid&3).
__global__ __launch_bounds__(256) void k_flash(const bf16* __restrict__ fused,
                                               bf16* __restrict__ obuf) {
  __shared__ float Qs[64][129];  // pitch 129: bank = (r+d)%32, conflict-free row reads
  __shared__ float Ks[32][133];  // pitch 133: bank = (5j+d)%32, quad-distinct
  __shared__ float Vs[32][133];
  __shared__ float Ps[64][33];
  int qb = blockIdx.x, bh = blockIdx.y;
  int b = bh >> 4, h = bh & 15;
  int tid = threadIdx.x;
  int r = tid >> 2, quad = tid & 3;

  for (int i = tid; i < 64 * 16; i += 256) {
    int rr = i >> 4, g = i & 15;
    const bf16* src = fused + (size_t)(b * SS + qb * 64 + rr) * NFF + h * DHH + g * 8;
    #pragma unroll
    for (int t = 0; t < 8; t++) Qs[rr][g * 8 + t] = __bfloat162float(src[t]);
  }

  float o[32];
  #pragma unroll
  for (int c = 0; c < 32; c++) o[c] = 0.f;
  float m_i = -1e30f, l_i = 0.f;
  int qrow = qb * 64 + r;
  int ntiles = 2 * qb + 2;

  for (int kt = 0; kt < ntiles; kt++) {
    __syncthreads();
    for (int i = tid; i < 32 * 16; i += 256) {
      int j = i >> 4, g = i & 15;
      const bf16* ksrc = fused + (size_t)(b * SS + kt * 32 + j) * NFF + DD + h * DHH + g * 8;
      const bf16* vsrc = ksrc + DD;
      #pragma unroll
      for (int t = 0; t < 8; t++) {
        Ks[j][g * 8 + t] = __bfloat162float(ksrc[t]);
        Vs[j][g * 8 + t] = __bfloat162float(vsrc[t]);
      }
    }
    __syncthreads();

    float sc[8];
    #pragma unroll
    for (int jj = 0; jj < 8; jj++) sc[jj] = 0.f;
    for (int d = 0; d < DHH; d++) {
      float qv = Qs[r][d];
      #pragma unroll
      for (int jj = 0; jj < 8; jj++) sc[jj] += qv * Ks[quad * 8 + jj][d];
    }
    float tmax = -1e30f;
    #pragma unroll
    for (int jj = 0; jj < 8; jj++) {
      int kk = kt * 32 + quad * 8 + jj;
      if (kk > qrow) sc[jj] = -1e30f;
      tmax = fmaxf(tmax, sc[jj]);
    }
    tmax = fmaxf(tmax, __shfl_xor(tmax, 1));
    tmax = fmaxf(tmax, __shfl_xor(tmax, 2));
    float mnew = fmaxf(m_i, tmax);
    float lsum = 0.f;
    #pragma unroll
    for (int jj = 0; jj < 8; jj++) {
      float p = __expf(sc[jj] - mnew);
      Ps[r][quad * 8 + jj] = p;
      lsum += p;
    }
    lsum += __shfl_xor(lsum, 1);
    lsum += __shfl_xor(lsum, 2);
    float alpha = __expf(m_i - mnew);
    l_i = l_i * alpha + lsum;
    m_i = mnew;
    #pragma unroll
    for (int c = 0; c < 32; c++) o[c] *= alpha;
    __syncthreads();
    int c0 = quad * 32;
    for (int jj = 0; jj < 32; jj++) {
      int j = (jj + quad * 8) & 31;   // rotate start to de-conflict banks
      float pv = Ps[r][j];
      #pragma unroll
      for (int c = 0; c < 32; c++) o[c] += pv * Vs[j][c0 + c];
    }
  }

  float inv = 1.f / l_i;
  bf16* dst = obuf + (size_t)(b * SS + qrow) * DD + h * DHH + quad * 32;
  #pragma unroll
  for (int c = 0; c < 32; c++) dst[c] = __float2bfloat16(o[c] * inv);
}

// ---------------- LayerNorm(ff) + ReLU -> h (bf16) ----------------
__global__ __launch_bounds__(256) void k_ln1_relu(const bf16* __restrict__ fused,
                                                  const float* __restrict__ gamma,
                                                  const float* __restrict__ beta,
                                                  bf16* __restrict__ h) {
  int row = blockIdx.x;
  const bf16* xr = fused + (size_t)row * NFF + 3 * DD;
  int tid = threadIdx.x;
  float s = 0.f, ss = 0.f;
  for (int i = tid; i < FFF; i += 256) {
    float v = __bfloat162float(xr[i]);
    s += v; ss += v * v;
  }
  #pragma unroll
  for (int off = 32; off > 0; off >>= 1) { s += __shfl_down(s, off); ss += __shfl_down(ss, off); }
  __shared__ float red[8];
  int wave = tid >> 6, lane = tid & 63;
  if (lane == 0) { red[wave] = s; red[4 + wave] = ss; }
  __syncthreads();
  if (tid == 0) {
    float S0 = red[0] + red[1] + red[2] + red[3];
    float SQ = red[4] + red[5] + red[6] + red[7];
    float m = S0 / FFF;
    float var = SQ / FFF - m * m;
    red[0] = m;
    red[1] = 1.f / sqrtf(var + LNEPS);
  }
  __syncthreads();
  float m = red[0], inv = red[1];
  for (int i = tid; i < FFF; i += 256) {
    float v = __bfloat162float(xr[i]);
    float y = gamma[i] * (v - m) * inv + beta[i];
    h[(size_t)row * FFF + i] = __float2bfloat16(fmaxf(y, 0.f));
  }
}

// ---------------- final LayerNorm (f32 in -> f32 out) ----------------
__global__ __launch_bounds__(256) void k_ln2(const float* __restrict__ yin,
                                             const float* __restrict__ gamma,
                                             const float* __restrict__ beta,
                                             float* __restrict__ out) {
  int row = blockIdx.x;
  const float* xr = yin + (size_t)row * DD;
  int tid = threadIdx.x;
  float s = 0.f, ss = 0.f;
  for (int i = tid; i < DD; i += 256) {
    float v = xr[i];
    s += v; ss += v * v;
  }
  #pragma unroll
  for (int off = 32; off > 0; off >>= 1) { s += __shfl_down(s, off); ss += __shfl_down(ss, off); }
  __shared__ float red[8];
  int wave = tid >> 6, lane = tid & 63;
  if (lane == 0) { red[wave] = s; red[4 + wave] = ss; }
  __syncthreads();
  if (tid == 0) {
    float S0 = red[0] + red[1] + red[2] + red[3];
    float SQ = red[4] + red[5] + red[6] + red[7];
    float m = S0 / DD;
    float var = SQ / DD - m * m;
    red[0] = m;
    red[1] = 1.f / sqrtf(var + LNEPS);
  }
  __syncthreads();
  float m = red[0], inv = red[1];
  for (int i = tid; i < DD; i += 256) {
    float v = xr[i];
    out[(size_t)row * DD + i] = gamma[i] * (v - m) * inv + beta[i];
  }
}

extern "C" void kernel_launch(void* const* d_in, const int* in_sizes, int n_in,
                              void* d_out, int out_size, void* d_ws, size_t ws_size,
                              hipStream_t stream) {
  const float* x       = (const float*)d_in[0];
  const float* W_fused = (const float*)d_in[1];
  const float* b_fused = (const float*)d_in[2];
  const float* W_attn  = (const float*)d_in[3];
  const float* b_attn  = (const float*)d_in[4];
  const float* W_ff    = (const float*)d_in[5];
  const float* b_ff    = (const float*)d_in[6];
  const float* gamma1  = (const float*)d_in[7];
  const float* beta1   = (const float*)d_in[8];
  const float* gamma2  = (const float*)d_in[9];
  const float* beta2   = (const float*)d_in[10];
  const float* rope_w  = (const float*)d_in[11];

  char* ws = (char*)d_ws;
  size_t off = 0;
  auto alloc = [&](size_t bytes) -> void* {
    void* p = ws + off;
    off += (bytes + 255) & ~(size_t)255;
    return p;
  };
  bf16* fused = (bf16*)alloc((size_t)MR * NFF * 2);   // 112 MiB
  bf16* xb    = (bf16*)alloc((size_t)MR * DD * 2);    // 16 MiB
  bf16* WfT   = (bf16*)alloc((size_t)NFF * DD * 2);   // 56 MiB
  bf16* WaT   = (bf16*)alloc((size_t)DD * DD * 2);    // 8 MiB
  bf16* WffT  = (bf16*)alloc((size_t)DD * FFF * 2);   // 32 MiB
  bf16* hbuf  = (bf16*)alloc((size_t)MR * FFF * 2);   // 64 MiB
  bf16* obuf  = (bf16*)alloc((size_t)MR * DD * 2);    // 16 MiB
  float* ybuf = (float*)alloc((size_t)MR * DD * 4);   // 32 MiB
  if (off > ws_size) return;  // workspace too small — fail visibly

  // 1. convert x -> bf16
  k_convert<<<(MR * DD / 4 + 255) / 256, 256, 0, stream>>>(x, xb, MR * DD / 4);
  // 2. transpose weights -> bf16 B^T
  k_transpose<<<dim3(NFF / 32, DD / 32), dim3(32, 8), 0, stream>>>(W_fused, WfT, DD, NFF);
  k_transpose<<<dim3(DD / 32, DD / 32), dim3(32, 8), 0, stream>>>(W_attn, WaT, DD, DD);
  k_transpose<<<dim3(DD / 32, FFF / 32), dim3(32, 8), 0, stream>>>(W_ff, WffT, FFF, DD);
  // 3. fused = x @ W_fused + b_fused   (bf16 out)
  k_gemm_bt<<<dim3(NFF / 64, MR / 64), 256, 0, stream>>>(xb, WfT, b_fused, fused, nullptr,
                                                         MR, NFF, DD, 1);
  // 4. RoPE on q,k
  k_rope<<<MR, 256, 0, stream>>>(fused, rope_w);
  // 5. causal flash attention -> obuf (bf16)
  k_flash<<<dim3(SS / 64, BB * HHN), 256, 0, stream>>>(fused, obuf);
  // 6. attn = o @ W_attn + b_attn   (f32 out -> ybuf)
  k_gemm_bt<<<dim3(DD / 64, MR / 64), 256, 0, stream>>>(obuf, WaT, b_attn, ybuf, nullptr,
                                                        MR, DD, DD, 0);
  // 7. h = relu(layernorm(ff))   (bf16)
  k_ln1_relu<<<MR, 256, 0, stream>>>(fused, gamma1, beta1, hbuf);
  // 8. ybuf = attn + silu(h @ W_ff + b_ff)   (in-place add, f32)
  k_gemm_bt<<<dim3(DD / 64, MR / 64), 256, 0, stream>>>(hbuf, WffT, b_ff, ybuf, ybuf,
                                                        MR, DD, FFF, 2);
  // 9. out = layernorm(ybuf)
  k_ln2<<<MR, 256, 0, stream>>>(ybuf, gamma2, beta2, (float*)d_out);
}

// Round 2
// 1666.465 us; speedup vs baseline: 2.1880x; 2.1880x over previous
//
#include <hip/hip_runtime.h>
#include <hip/hip_bf16.h>
#include <cmath>

#define BB 2
#define SS 2048
#define DD 2048
#define HHN 16
#define DHH 128
#define FFF 8192
#define NFF (3*DD+FFF)   // 14336
#define MR (BB*SS)       // 4096
#define LNEPS 1e-6f

typedef __hip_bfloat16 bf16;
using bf16x8 = __attribute__((ext_vector_type(8))) __bf16;
using f32x4  = __attribute__((ext_vector_type(4))) float;

// ---------------- convert f32 -> bf16 (vectorized) ----------------
__global__ __launch_bounds__(256) void k_convert(const float* __restrict__ in,
                                                 bf16* __restrict__ out, int n4) {
  int i = blockIdx.x * 256 + threadIdx.x;
  if (i >= n4) return;
  float4 v = ((const float4*)in)[i];
  out[4*i+0] = __float2bfloat16(v.x);
  out[4*i+1] = __float2bfloat16(v.y);
  out[4*i+2] = __float2bfloat16(v.z);
  out[4*i+3] = __float2bfloat16(v.w);
}

// ---------------- transpose+convert: in (R x C) f32 -> out (C x R) bf16 ----------------
__global__ __launch_bounds__(256) void k_transpose(const float* __restrict__ in,
                                                   bf16* __restrict__ out, int R, int C) {
  __shared__ float tile[32][33];
  int c0 = blockIdx.x * 32, r0 = blockIdx.y * 32;
  int tx = threadIdx.x, ty = threadIdx.y;
  #pragma unroll
  for (int i = 0; i < 32; i += 8)
    tile[ty + i][tx] = in[(size_t)(r0 + ty + i) * C + (c0 + tx)];
  __syncthreads();
  #pragma unroll
  for (int i = 0; i < 32; i += 8)
    out[(size_t)(c0 + ty + i) * R + (r0 + tx)] = __float2bfloat16(tile[tx][ty + i]);
}

// ---------------- bf16 MFMA GEMM: C[MxN] = A[MxK] @ BT[NxK]^T + bias ----------------
// mode 0: C f32 = v ; mode 1: C bf16 = v ; mode 2: C f32 = addin + silu(v)
__global__ __launch_bounds__(256) void k_gemm_bt(const bf16* __restrict__ A,
                                                 const bf16* __restrict__ BT,
                                                 const float* __restrict__ bias,
                                                 void* __restrict__ Cout,
                                                 const float* __restrict__ addin,
                                                 int M, int N, int K, int mode) {
  constexpr int LDT = 40;  // bf16 pitch: 80B rows, 16B-aligned, 2-way-max bank alias (free)
  __shared__ __align__(16) bf16 As[64 * LDT];
  __shared__ __align__(16) bf16 Bs[64 * LDT];
  int tid = threadIdx.x;
  int wave = tid >> 6, lane = tid & 63;
  int wm = wave >> 1, wn = wave & 1;
  int l15 = lane & 15, l4 = lane >> 4;
  int m0 = blockIdx.y * 64, n0 = blockIdx.x * 64;
  int sr = tid >> 2;          // staging row 0..63
  int sc = (tid & 3) * 8;     // staging k-offset
  const bf16* Aptr = A + (size_t)(m0 + sr) * K + sc;
  const bf16* Bptr = BT + (size_t)(n0 + sr) * K + sc;

  f32x4 acc[2][2];
  #pragma unroll
  for (int i = 0; i < 2; i++)
    #pragma unroll
    for (int j = 0; j < 2; j++)
      acc[i][j] = f32x4{0.f, 0.f, 0.f, 0.f};

  for (int k0 = 0; k0 < K; k0 += 32) {
    __syncthreads();
    *reinterpret_cast<bf16x8*>(&As[sr * LDT + sc]) =
        *reinterpret_cast<const bf16x8*>(Aptr + k0);
    *reinterpret_cast<bf16x8*>(&Bs[sr * LDT + sc]) =
        *reinterpret_cast<const bf16x8*>(Bptr + k0);
    __syncthreads();
    bf16x8 a0 = *reinterpret_cast<const bf16x8*>(&As[(wm * 32 + l15) * LDT + l4 * 8]);
    bf16x8 a1 = *reinterpret_cast<const bf16x8*>(&As[(wm * 32 + 16 + l15) * LDT + l4 * 8]);
    bf16x8 b0 = *reinterpret_cast<const bf16x8*>(&Bs[(wn * 32 + l15) * LDT + l4 * 8]);
    bf16x8 b1 = *reinterpret_cast<const bf16x8*>(&Bs[(wn * 32 + 16 + l15) * LDT + l4 * 8]);
    acc[0][0] = __builtin_amdgcn_mfma_f32_16x16x32_bf16(a0, b0, acc[0][0], 0, 0, 0);
    acc[0][1] = __builtin_amdgcn_mfma_f32_16x16x32_bf16(a0, b1, acc[0][1], 0, 0, 0);
    acc[1][0] = __builtin_amdgcn_mfma_f32_16x16x32_bf16(a1, b0, acc[1][0], 0, 0, 0);
    acc[1][1] = __builtin_amdgcn_mfma_f32_16x16x32_bf16(a1, b1, acc[1][1], 0, 0, 0);
  }

  float* Cf = (float*)Cout;
  bf16* Cb = (bf16*)Cout;
  #pragma unroll
  for (int i = 0; i < 2; i++) {
    #pragma unroll
    for (int j = 0; j < 2; j++) {
      int mbase = m0 + wm * 32 + i * 16 + l4 * 4;
      int nn = n0 + wn * 32 + j * 16 + l15;
      float bv = bias[nn];
      #pragma unroll
      for (int rr = 0; rr < 4; rr++) {
        size_t idx = (size_t)(mbase + rr) * N + nn;
        float v = acc[i][j][rr] + bv;
        if (mode == 0) {
          Cf[idx] = v;
        } else if (mode == 1) {
          Cb[idx] = __float2bfloat16(v);
        } else {
          float sig = 1.f / (1.f + expf(-v));
          Cf[idx] = addin[idx] + v * sig;
        }
      }
    }
  }
}

// ---------------- RoPE in-place on q,k regions of fused (bf16) ----------------
// ref rotate_half has NO negation: rh[d]=x[d+64] (d<64), rh[d]=x[d-64] (d>=64)
__global__ __launch_bounds__(256) void k_rope(bf16* __restrict__ fused,
                                              const float* __restrict__ rope_w) {
  int row = blockIdx.x;
  int s = row & (SS - 1);
  const float* rw = rope_w + (size_t)s * DHH;
  const float scale = 0.08838834764831845f;  // 1/sqrt(128)
  for (int idx = threadIdx.x; idx < HHN * 64; idx += 256) {
    int h = idx >> 6, d = idx & 63;
    float c1 = cosf(rw[d]),      s1 = sinf(rw[d]);
    float c2 = cosf(rw[d + 64]), s2 = sinf(rw[d + 64]);
    bf16* q = fused + (size_t)row * NFF + h * DHH;
    bf16* k = q + DD;
    float q0 = __bfloat162float(q[d]), q1 = __bfloat162float(q[d + 64]);
    q[d]      = __float2bfloat16((q0 * c1 + q1 * s1) * scale);
    q[d + 64] = __float2bfloat16((q1 * c2 + q0 * s2) * scale);
    float k0 = __bfloat162float(k[d]), k1 = __bfloat162float(k[d + 64]);
    k[d]      = __float2bfloat16(k0 * c1 + k1 * s1);
    k[d + 64] = __float2bfloat16(k1 * c2 + k0 * s2);
  }
}

// ---------------- causal flash attention, MFMA (bf16 matmuls, fp32 softmax) ----------------
// grid: (S/64, B*H), 256 threads = 4 waves. Wave w owns q-rows [w*16, w*16+16).
// MFMA 16x16x32 conventions (verified by k_gemm_bt passing):
//   A-frag: lane holds A[m = l&15][k = (l>>4)*8 + j], j=0..7  (bf16x8)
//   B-frag: lane holds BT[n = l&15][k = (l>>4)*8 + j]          (BT is NxK row-major)
//   C/D   : lane reg r holds C[row = (l>>4)*4 + r][col = l&15]
__global__ __launch_bounds__(256) void k_flash(const bf16* __restrict__ fused,
                                               bf16* __restrict__ obuf) {
  constexpr int LDP = 72;  // bf16 pitch = 144B: 16B-aligned, stride 9 (odd) in 16B units
                           // -> any 8 consecutive rows map to distinct 16B bank-groups
  __shared__ __align__(16) bf16 Qs[64 * LDP];   //  9 KiB
  __shared__ __align__(16) bf16 Ks[64 * LDP];   //  9 KiB
  __shared__ __align__(16) bf16 Vt[128 * LDP];  // 18 KiB (V transposed: [d][key])
  __shared__ __align__(16) bf16 Ps[64 * LDP];   //  9 KiB (per-wave-private strips)
  int qb = blockIdx.x, bh = blockIdx.y;
  int b = bh >> 4, h = bh & 15;
  int tid = threadIdx.x;
  int wave = tid >> 6, lane = tid & 63;
  int l15 = lane & 15, g = lane >> 4;  // g = 0..3

  const bf16* qbase = fused + (size_t)(b * SS + qb * 64) * NFF + h * DHH;
  const bf16* kbase = fused + (size_t)(b * SS) * NFF + DD + h * DHH;
  const bf16* vbase = kbase + DD;

  // ---- stage Q (64 x 128) ----
  {
    int r = tid >> 4, dc = tid & 15;  // 16 threads per row, 16B chunks
    #pragma unroll
    for (int i = 0; i < 4; i++) {
      int row = r + 16 * i;
      *reinterpret_cast<bf16x8*>(&Qs[row * LDP + dc * 8]) =
          *reinterpret_cast<const bf16x8*>(qbase + (size_t)row * NFF + dc * 8);
    }
  }
  __syncthreads();
  // Q fragments for this wave's 16-row strip, hoisted to registers (K=128 -> 4 ksteps)
  bf16x8 qf[4];
  #pragma unroll
  for (int ks = 0; ks < 4; ks++)
    qf[ks] = *reinterpret_cast<const bf16x8*>(&Qs[(wave * 16 + l15) * LDP + ks * 32 + g * 8]);

  f32x4 o[8];
  #pragma unroll
  for (int nt = 0; nt < 8; nt++) o[nt] = f32x4{0.f, 0.f, 0.f, 0.f};
  float m_i[4], l_i[4];
  #pragma unroll
  for (int r = 0; r < 4; r++) { m_i[r] = -1e30f; l_i[r] = 0.f; }
  int qrow_base = qb * 64 + wave * 16 + g * 4;  // + r

  for (int kt = 0; kt <= qb; kt++) {
    __syncthreads();  // protect Ks/Vt from previous iteration's readers
    // ---- stage K tile (64 keys x 128 d), row-major ----
    {
      int r = tid >> 4, dc = tid & 15;
      #pragma unroll
      for (int i = 0; i < 4; i++) {
        int key = r + 16 * i;
        *reinterpret_cast<bf16x8*>(&Ks[key * LDP + dc * 8]) =
            *reinterpret_cast<const bf16x8*>(kbase + (size_t)(kt * 64 + key) * NFF + dc * 8);
      }
      // ---- stage V tile transposed: Vt[d][key] ----
      // lane -> key = tid&63 (consecutive): ds_write_u16 addrs are 32 consecutive
      // dwords per instr -> conflict-free. Scattered 16B global reads are
      // L1-absorbed (full lines consumed across waves within this barrier window).
      int vkey = tid & 63, dc0 = tid >> 6;  // dc0 = 0..3
      #pragma unroll
      for (int i = 0; i < 4; i++) {
        int dchunk = dc0 + i * 4;  // 0..15
        bf16x8 vv = *reinterpret_cast<const bf16x8*>(
            vbase + (size_t)(kt * 64 + vkey) * NFF + dchunk * 8);
        #pragma unroll
        for (int j = 0; j < 8; j++)
          *(__bf16*)&Vt[(dchunk * 8 + j) * LDP + vkey] = vv[j];
      }
    }
    __syncthreads();

    // ---- S strip = Q_strip (16x128) @ K_tile^T (128x64) ----
    f32x4 s[4];
    #pragma unroll
    for (int nt = 0; nt < 4; nt++) {
      s[nt] = f32x4{0.f, 0.f, 0.f, 0.f};
      #pragma unroll
      for (int ks = 0; ks < 4; ks++) {
        bf16x8 bfrag = *reinterpret_cast<const bf16x8*>(
            &Ks[(nt * 16 + l15) * LDP + ks * 32 + g * 8]);
        s[nt] = __builtin_amdgcn_mfma_f32_16x16x32_bf16(qf[ks], bfrag, s[nt], 0, 0, 0);
      }
    }
    // ---- causal mask + online softmax ----
    #pragma unroll
    for (int nt = 0; nt < 4; nt++) {
      int kk = kt * 64 + nt * 16 + l15;
      #pragma unroll
      for (int r = 0; r < 4; r++)
        if (kk > qrow_base + r) s[nt][r] = -1e30f;
    }
    float alpha[4];
    #pragma unroll
    for (int r = 0; r < 4; r++) {
      float mx = fmaxf(fmaxf(s[0][r], s[1][r]), fmaxf(s[2][r], s[3][r]));
      mx = fmaxf(mx, __shfl_xor(mx, 1));
      mx = fmaxf(mx, __shfl_xor(mx, 2));
      mx = fmaxf(mx, __shfl_xor(mx, 4));
      mx = fmaxf(mx, __shfl_xor(mx, 8));
      float mnew = fmaxf(m_i[r], mx);
      alpha[r] = __expf(m_i[r] - mnew);
      m_i[r] = mnew;
      float ls = 0.f;
      #pragma unroll
      for (int nt = 0; nt < 4; nt++) {
        float p = __expf(s[nt][r] - mnew);
        s[nt][r] = p;
        ls += p;
      }
      ls += __shfl_xor(ls, 1);
      ls += __shfl_xor(ls, 2);
      ls += __shfl_xor(ls, 4);
      ls += __shfl_xor(ls, 8);
      l_i[r] = l_i[r] * alpha[r] + ls;
    }
    // ---- write P (bf16) to this wave's private Ps strip (C-layout -> A-layout) ----
    #pragma unroll
    for (int nt = 0; nt < 4; nt++)
      #pragma unroll
      for (int r = 0; r < 4; r++)
        *(__bf16*)&Ps[(wave * 16 + g * 4 + r) * LDP + nt * 16 + l15] = (__bf16)s[nt][r];
    // ---- rescale O ----
    #pragma unroll
    for (int nt = 0; nt < 8; nt++)
      #pragma unroll
      for (int r = 0; r < 4; r++) o[nt][r] *= alpha[r];
    // ---- O_strip (16x128) += P_strip (16x64) @ V_tile (64x128) ----
    bf16x8 pf[2];
    #pragma unroll
    for (int ks = 0; ks < 2; ks++)
      pf[ks] = *reinterpret_cast<const bf16x8*>(
          &Ps[(wave * 16 + l15) * LDP + ks * 32 + g * 8]);
    #pragma unroll
    for (int nt = 0; nt < 8; nt++)
      #pragma unroll
      for (int ks = 0; ks < 2; ks++) {
        bf16x8 bfrag = *reinterpret_cast<const bf16x8*>(
            &Vt[(nt * 16 + l15) * LDP + ks * 32 + g * 8]);
        o[nt] = __builtin_amdgcn_mfma_f32_16x16x32_bf16(pf[ks], bfrag, o[nt], 0, 0, 0);
      }
  }

  // ---- epilogue: O / l -> obuf ----
  float inv[4];
  #pragma unroll
  for (int r = 0; r < 4; r++) inv[r] = 1.f / l_i[r];
  #pragma unroll
  for (int nt = 0; nt < 8; nt++)
    #pragma unroll
    for (int r = 0; r < 4; r++) {
      size_t row = (size_t)(b * SS + qrow_base + r);
      obuf[row * DD + h * DHH + nt * 16 + l15] = __float2bfloat16(o[nt][r] * inv[r]);
    }
}

// ---------------- LayerNorm(ff) + ReLU -> h (bf16) ----------------
__global__ __launch_bounds__(256) void k_ln1_relu(const bf16* __restrict__ fused,
                                                  const float* __restrict__ gamma,
                                                  const float* __restrict__ beta,
                                                  bf16* __restrict__ h) {
  int row = blockIdx.x;
  const bf16* xr = fused + (size_t)row * NFF + 3 * DD;
  int tid = threadIdx.x;
  float s = 0.f, ss = 0.f;
  for (int i = tid; i < FFF; i += 256) {
    float v = __bfloat162float(xr[i]);
    s += v; ss += v * v;
  }
  #pragma unroll
  for (int off = 32; off > 0; off >>= 1) { s += __shfl_down(s, off); ss += __shfl_down(ss, off); }
  __shared__ float red[8];
  int wave = tid >> 6, lane = tid & 63;
  if (lane == 0) { red[wave] = s; red[4 + wave] = ss; }
  __syncthreads();
  if (tid == 0) {
    float S0 = red[0] + red[1] + red[2] + red[3];
    float SQ = red[4] + red[5] + red[6] + red[7];
    float m = S0 / FFF;
    float var = SQ / FFF - m * m;
    red[0] = m;
    red[1] = 1.f / sqrtf(var + LNEPS);
  }
  __syncthreads();
  float m = red[0], inv = red[1];
  for (int i = tid; i < FFF; i += 256) {
    float v = __bfloat162float(xr[i]);
    float y = gamma[i] * (v - m) * inv + beta[i];
    h[(size_t)row * FFF + i] = __float2bfloat16(fmaxf(y, 0.f));
  }
}

// ---------------- final LayerNorm (f32 in -> f32 out) ----------------
__global__ __launch_bounds__(256) void k_ln2(const float* __restrict__ yin,
                                             const float* __restrict__ gamma,
                                             const float* __restrict__ beta,
                                             float* __restrict__ out) {
  int row = blockIdx.x;
  const float* xr = yin + (size_t)row * DD;
  int tid = threadIdx.x;
  float s = 0.f, ss = 0.f;
  for (int i = tid; i < DD; i += 256) {
    float v = xr[i];
    s += v; ss += v * v;
  }
  #pragma unroll
  for (int off = 32; off > 0; off >>= 1) { s += __shfl_down(s, off); ss += __shfl_down(ss, off); }
  __shared__ float red[8];
  int wave = tid >> 6, lane = tid & 63;
  if (lane == 0) { red[wave] = s; red[4 + wave] = ss; }
  __syncthreads();
  if (tid == 0) {
    float S0 = red[0] + red[1] + red[2] + red[3];
    float SQ = red[4] + red[5] + red[6] + red[7];
    float m = S0 / DD;
    float var = SQ / DD - m * m;
    red[0] = m;
    red[1] = 1.f / sqrtf(var + LNEPS);
  }
  __syncthreads();
  float m = red[0], inv = red[1];
  for (int i = tid; i < DD; i += 256) {
    float v = xr[i];
    out[(size_t)row * DD + i] = gamma[i] * (v - m) * inv + beta[i];
  }
}

extern "C" void kernel_launch(void* const* d_in, const int* in_sizes, int n_in,
                              void* d_out, int out_size, void* d_ws, size_t ws_size,
                              hipStream_t stream) {
  const float* x       = (const float*)d_in[0];
  const float* W_fused = (const float*)d_in[1];
  const float* b_fused = (const float*)d_in[2];
  const float* W_attn  = (const float*)d_in[3];
  const float* b_attn  = (const float*)d_in[4];
  const float* W_ff    = (const float*)d_in[5];
  const float* b_ff    = (const float*)d_in[6];
  const float* gamma1  = (const float*)d_in[7];
  const float* beta1   = (const float*)d_in[8];
  const float* gamma2  = (const float*)d_in[9];
  const float* beta2   = (const float*)d_in[10];
  const float* rope_w  = (const float*)d_in[11];

  char* ws = (char*)d_ws;
  size_t off = 0;
  auto alloc = [&](size_t bytes) -> void* {
    void* p = ws + off;
    off += (bytes + 255) & ~(size_t)255;
    return p;
  };
  bf16* fused = (bf16*)alloc((size_t)MR * NFF * 2);   // 112 MiB
  bf16* xb    = (bf16*)alloc((size_t)MR * DD * 2);    // 16 MiB
  bf16* WfT   = (bf16*)alloc((size_t)NFF * DD * 2);   // 56 MiB
  bf16* WaT   = (bf16*)alloc((size_t)DD * DD * 2);    // 8 MiB
  bf16* WffT  = (bf16*)alloc((size_t)DD * FFF * 2);   // 32 MiB
  bf16* hbuf  = (bf16*)alloc((size_t)MR * FFF * 2);   // 64 MiB
  bf16* obuf  = (bf16*)alloc((size_t)MR * DD * 2);    // 16 MiB
  float* ybuf = (float*)alloc((size_t)MR * DD * 4);   // 32 MiB
  if (off > ws_size) return;  // workspace too small — fail visibly

  // 1. convert x -> bf16
  k_convert<<<(MR * DD / 4 + 255) / 256, 256, 0, stream>>>(x, xb, MR * DD / 4);
  // 2. transpose weights -> bf16 B^T
  k_transpose<<<dim3(NFF / 32, DD / 32), dim3(32, 8), 0, stream>>>(W_fused, WfT, DD, NFF);
  k_transpose<<<dim3(DD / 32, DD / 32), dim3(32, 8), 0, stream>>>(W_attn, WaT, DD, DD);
  k_transpose<<<dim3(DD / 32, FFF / 32), dim3(32, 8), 0, stream>>>(W_ff, WffT, FFF, DD);
  // 3. fused = x @ W_fused + b_fused   (bf16 out)
  k_gemm_bt<<<dim3(NFF / 64, MR / 64), 256, 0, stream>>>(xb, WfT, b_fused, fused, nullptr,
                                                         MR, NFF, DD, 1);
  // 4. RoPE on q,k
  k_rope<<<MR, 256, 0, stream>>>(fused, rope_w);
  // 5. causal flash attention (MFMA) -> obuf (bf16)
  k_flash<<<dim3(SS / 64, BB * HHN), 256, 0, stream>>>(fused, obuf);
  // 6. attn = o @ W_attn + b_attn   (f32 out -> ybuf)
  k_gemm_bt<<<dim3(DD / 64, MR / 64), 256, 0, stream>>>(obuf, WaT, b_attn, ybuf, nullptr,
                                                        MR, DD, DD, 0);
  // 7. h = relu(layernorm(ff))   (bf16)
  k_ln1_relu<<<MR, 256, 0, stream>>>(fused, gamma1, beta1, hbuf);
  // 8. ybuf = attn + silu(h @ W_ff + b_ff)   (in-place add, f32)
  k_gemm_bt<<<dim3(DD / 64, MR / 64), 256, 0, stream>>>(hbuf, WffT, b_ff, ybuf, ybuf,
                                                        MR, DD, FFF, 2);
  // 9. out = layernorm(ybuf)
  k_ln2<<<MR, 256, 0, stream>>>(ybuf, gamma2, beta2, (float*)d_out);
}

// Round 3
// 1305.133 us; speedup vs baseline: 2.7938x; 1.2769x over previous
//
#include <hip/hip_runtime.h>
#include <hip/hip_bf16.h>
#include <cmath>

#define BB 2
#define SS 2048
#define DD 2048
#define HHN 16
#define DHH 128
#define FFF 8192
#define NFF (3*DD+FFF)   // 14336
#define MR (BB*SS)       // 4096
#define LNEPS 1e-6f

typedef __hip_bfloat16 bf16;
using bf16x8 = __attribute__((ext_vector_type(8))) __bf16;
using f32x4  = __attribute__((ext_vector_type(4))) float;

// async global->LDS copy, 16B per lane (m97: the 874-TF enabler)
__device__ __forceinline__ void async_copy16(const bf16* g, bf16* l) {
  __builtin_amdgcn_global_load_lds(
      (const __attribute__((address_space(1))) void*)g,
      (__attribute__((address_space(3))) void*)l, 16, 0, 0);
}

// ---------------- convert f32 -> bf16 (vectorized) ----------------
__global__ __launch_bounds__(256) void k_convert(const float* __restrict__ in,
                                                 bf16* __restrict__ out, int n4) {
  int i = blockIdx.x * 256 + threadIdx.x;
  if (i >= n4) return;
  float4 v = ((const float4*)in)[i];
  out[4*i+0] = __float2bfloat16(v.x);
  out[4*i+1] = __float2bfloat16(v.y);
  out[4*i+2] = __float2bfloat16(v.z);
  out[4*i+3] = __float2bfloat16(v.w);
}

// ---------------- transpose+convert: in (R x C) f32 -> out (C x R) bf16 ----------------
__global__ __launch_bounds__(256) void k_transpose(const float* __restrict__ in,
                                                   bf16* __restrict__ out, int R, int C) {
  __shared__ float tile[32][33];
  int c0 = blockIdx.x * 32, r0 = blockIdx.y * 32;
  int tx = threadIdx.x, ty = threadIdx.y;
  #pragma unroll
  for (int i = 0; i < 32; i += 8)
    tile[ty + i][tx] = in[(size_t)(r0 + ty + i) * C + (c0 + tx)];
  __syncthreads();
  #pragma unroll
  for (int i = 0; i < 32; i += 8)
    out[(size_t)(c0 + ty + i) * R + (r0 + tx)] = __float2bfloat16(tile[tx][ty + i]);
}

// ---------------- bf16 MFMA GEMM, 128x128 tile (m97 structure) ----------------
// C[MxN] = A[MxK] @ BT[NxK]^T + bias
// mode 0: C f32 = v ; mode 1: C bf16 = v ; mode 2: C f32 = addin + silu(v)
// 256 threads = 4 waves in 2x2; each wave owns a 64x64 region (4x4 MFMA 16x16x32).
// LDS unpadded [128][32] row-major — required by global_load_lds lane scatter.
__global__ __launch_bounds__(256) void k_gemm_bt(const bf16* __restrict__ A,
                                                 const bf16* __restrict__ BT,
                                                 const float* __restrict__ bias,
                                                 void* __restrict__ Cout,
                                                 const float* __restrict__ addin,
                                                 int M, int N, int K, int mode) {
  __shared__ __align__(16) bf16 As[128 * 32];  // 8 KiB
  __shared__ __align__(16) bf16 Bs[128 * 32];  // 8 KiB
  int tid = threadIdx.x;
  int w = tid >> 6, l = tid & 63;
  int wm = w >> 1, wn = w & 1;
  int l15 = l & 15, g = l >> 4;        // fragment coords
  int sr4 = l >> 2, sc4 = (l & 3) * 8; // staging coords (4 lanes/row, 8 bf16 each)
  int m0 = blockIdx.y * 128, n0 = blockIdx.x * 128;

  f32x4 acc[4][4];
  #pragma unroll
  for (int i = 0; i < 4; i++)
    #pragma unroll
    for (int j = 0; j < 4; j++)
      acc[i][j] = f32x4{0.f, 0.f, 0.f, 0.f};

  for (int k0 = 0; k0 < K; k0 += 32) {
    __syncthreads();  // previous tile's readers done
    #pragma unroll
    for (int i = 0; i < 2; i++) {
      int r = (w * 2 + i) * 16 + sr4;  // 0..127
      async_copy16(A + (size_t)(m0 + r) * K + k0 + sc4, &As[r * 32 + sc4]);
      async_copy16(BT + (size_t)(n0 + r) * K + k0 + sc4, &Bs[r * 32 + sc4]);
    }
    __syncthreads();  // drains vmcnt (global_load_lds) — m97 semantics

    bf16x8 af[4], bf_[4];
    #pragma unroll
    for (int i = 0; i < 4; i++)
      af[i] = *reinterpret_cast<const bf16x8*>(&As[(wm * 64 + i * 16 + l15) * 32 + g * 8]);
    #pragma unroll
    for (int j = 0; j < 4; j++)
      bf_[j] = *reinterpret_cast<const bf16x8*>(&Bs[(wn * 64 + j * 16 + l15) * 32 + g * 8]);
    #pragma unroll
    for (int i = 0; i < 4; i++)
      #pragma unroll
      for (int j = 0; j < 4; j++)
        acc[i][j] = __builtin_amdgcn_mfma_f32_16x16x32_bf16(af[i], bf_[j], acc[i][j], 0, 0, 0);
  }

  float* Cf = (float*)Cout;
  bf16* Cb = (bf16*)Cout;
  #pragma unroll
  for (int i = 0; i < 4; i++) {
    #pragma unroll
    for (int j = 0; j < 4; j++) {
      int mbase = m0 + wm * 64 + i * 16 + g * 4;
      int nn = n0 + wn * 64 + j * 16 + l15;
      float bv = bias[nn];
      #pragma unroll
      for (int rr = 0; rr < 4; rr++) {
        size_t idx = (size_t)(mbase + rr) * N + nn;
        float v = acc[i][j][rr] + bv;
        if (mode == 0) {
          Cf[idx] = v;
        } else if (mode == 1) {
          Cb[idx] = __float2bfloat16(v);
        } else {
          float sig = 1.f / (1.f + expf(-v));
          Cf[idx] = addin[idx] + v * sig;
        }
      }
    }
  }
}

// ---------------- RoPE in-place on q,k regions of fused (bf16) ----------------
// ref rotate_half has NO negation: rh[d]=x[d+64] (d<64), rh[d]=x[d-64] (d>=64)
__global__ __launch_bounds__(256) void k_rope(bf16* __restrict__ fused,
                                              const float* __restrict__ rope_w) {
  int row = blockIdx.x;
  int s = row & (SS - 1);
  const float* rw = rope_w + (size_t)s * DHH;
  const float scale = 0.08838834764831845f;  // 1/sqrt(128)
  for (int idx = threadIdx.x; idx < HHN * 64; idx += 256) {
    int h = idx >> 6, d = idx & 63;
    float c1 = cosf(rw[d]),      s1 = sinf(rw[d]);
    float c2 = cosf(rw[d + 64]), s2 = sinf(rw[d + 64]);
    bf16* q = fused + (size_t)row * NFF + h * DHH;
    bf16* k = q + DD;
    float q0 = __bfloat162float(q[d]), q1 = __bfloat162float(q[d + 64]);
    q[d]      = __float2bfloat16((q0 * c1 + q1 * s1) * scale);
    q[d + 64] = __float2bfloat16((q1 * c2 + q0 * s2) * scale);
    float k0 = __bfloat162float(k[d]), k1 = __bfloat162float(k[d + 64]);
    k[d]      = __float2bfloat16(k0 * c1 + k1 * s1);
    k[d + 64] = __float2bfloat16(k1 * c2 + k0 * s2);
  }
}

// ---------------- causal flash attention, MFMA (bf16 matmuls, fp32 softmax) ----------------
// grid: (S/64, B*H), 256 threads = 4 waves. Wave w owns q-rows [w*16, w*16+16).
__global__ __launch_bounds__(256) void k_flash(const bf16* __restrict__ fused,
                                               bf16* __restrict__ obuf) {
  constexpr int LDP = 72;  // bf16 pitch = 144B: 16B-aligned, odd 16B stride
  __shared__ __align__(16) bf16 Qs[64 * LDP];   //  9 KiB
  __shared__ __align__(16) bf16 Ks[64 * LDP];   //  9 KiB
  __shared__ __align__(16) bf16 Vt[128 * LDP];  // 18 KiB (V transposed: [d][key])
  __shared__ __align__(16) bf16 Ps[64 * LDP];   //  9 KiB (per-wave-private strips)
  int qb = blockIdx.x, bh = blockIdx.y;
  int b = bh >> 4, h = bh & 15;
  int tid = threadIdx.x;
  int wave = tid >> 6, lane = tid & 63;
  int l15 = lane & 15, g = lane >> 4;  // g = 0..3

  const bf16* qbase = fused + (size_t)(b * SS + qb * 64) * NFF + h * DHH;
  const bf16* kbase = fused + (size_t)(b * SS) * NFF + DD + h * DHH;
  const bf16* vbase = kbase + DD;

  // ---- stage Q (64 x 128) ----
  {
    int r = tid >> 4, dc = tid & 15;
    #pragma unroll
    for (int i = 0; i < 4; i++) {
      int row = r + 16 * i;
      *reinterpret_cast<bf16x8*>(&Qs[row * LDP + dc * 8]) =
          *reinterpret_cast<const bf16x8*>(qbase + (size_t)row * NFF + dc * 8);
    }
  }
  __syncthreads();
  bf16x8 qf[4];
  #pragma unroll
  for (int ks = 0; ks < 4; ks++)
    qf[ks] = *reinterpret_cast<const bf16x8*>(&Qs[(wave * 16 + l15) * LDP + ks * 32 + g * 8]);

  f32x4 o[8];
  #pragma unroll
  for (int nt = 0; nt < 8; nt++) o[nt] = f32x4{0.f, 0.f, 0.f, 0.f};
  float m_i[4], l_i[4];
  #pragma unroll
  for (int r = 0; r < 4; r++) { m_i[r] = -1e30f; l_i[r] = 0.f; }
  int qrow_base = qb * 64 + wave * 16 + g * 4;  // + r

  for (int kt = 0; kt <= qb; kt++) {
    __syncthreads();
    {
      int r = tid >> 4, dc = tid & 15;
      #pragma unroll
      for (int i = 0; i < 4; i++) {
        int key = r + 16 * i;
        *reinterpret_cast<bf16x8*>(&Ks[key * LDP + dc * 8]) =
            *reinterpret_cast<const bf16x8*>(kbase + (size_t)(kt * 64 + key) * NFF + dc * 8);
      }
      int vkey = tid & 63, dc0 = tid >> 6;
      #pragma unroll
      for (int i = 0; i < 4; i++) {
        int dchunk = dc0 + i * 4;
        bf16x8 vv = *reinterpret_cast<const bf16x8*>(
            vbase + (size_t)(kt * 64 + vkey) * NFF + dchunk * 8);
        #pragma unroll
        for (int j = 0; j < 8; j++)
          *(__bf16*)&Vt[(dchunk * 8 + j) * LDP + vkey] = vv[j];
      }
    }
    __syncthreads();

    f32x4 s[4];
    #pragma unroll
    for (int nt = 0; nt < 4; nt++) {
      s[nt] = f32x4{0.f, 0.f, 0.f, 0.f};
      #pragma unroll
      for (int ks = 0; ks < 4; ks++) {
        bf16x8 bfrag = *reinterpret_cast<const bf16x8*>(
            &Ks[(nt * 16 + l15) * LDP + ks * 32 + g * 8]);
        s[nt] = __builtin_amdgcn_mfma_f32_16x16x32_bf16(qf[ks], bfrag, s[nt], 0, 0, 0);
      }
    }
    #pragma unroll
    for (int nt = 0; nt < 4; nt++) {
      int kk = kt * 64 + nt * 16 + l15;
      #pragma unroll
      for (int r = 0; r < 4; r++)
        if (kk > qrow_base + r) s[nt][r] = -1e30f;
    }
    float alpha[4];
    #pragma unroll
    for (int r = 0; r < 4; r++) {
      float mx = fmaxf(fmaxf(s[0][r], s[1][r]), fmaxf(s[2][r], s[3][r]));
      mx = fmaxf(mx, __shfl_xor(mx, 1));
      mx = fmaxf(mx, __shfl_xor(mx, 2));
      mx = fmaxf(mx, __shfl_xor(mx, 4));
      mx = fmaxf(mx, __shfl_xor(mx, 8));
      float mnew = fmaxf(m_i[r], mx);
      alpha[r] = __expf(m_i[r] - mnew);
      m_i[r] = mnew;
      float ls = 0.f;
      #pragma unroll
      for (int nt = 0; nt < 4; nt++) {
        float p = __expf(s[nt][r] - mnew);
        s[nt][r] = p;
        ls += p;
      }
      ls += __shfl_xor(ls, 1);
      ls += __shfl_xor(ls, 2);
      ls += __shfl_xor(ls, 4);
      ls += __shfl_xor(ls, 8);
      l_i[r] = l_i[r] * alpha[r] + ls;
    }
    #pragma unroll
    for (int nt = 0; nt < 4; nt++)
      #pragma unroll
      for (int r = 0; r < 4; r++)
        *(__bf16*)&Ps[(wave * 16 + g * 4 + r) * LDP + nt * 16 + l15] = (__bf16)s[nt][r];
    #pragma unroll
    for (int nt = 0; nt < 8; nt++)
      #pragma unroll
      for (int r = 0; r < 4; r++) o[nt][r] *= alpha[r];
    bf16x8 pf[2];
    #pragma unroll
    for (int ks = 0; ks < 2; ks++)
      pf[ks] = *reinterpret_cast<const bf16x8*>(
          &Ps[(wave * 16 + l15) * LDP + ks * 32 + g * 8]);
    #pragma unroll
    for (int nt = 0; nt < 8; nt++)
      #pragma unroll
      for (int ks = 0; ks < 2; ks++) {
        bf16x8 bfrag = *reinterpret_cast<const bf16x8*>(
            &Vt[(nt * 16 + l15) * LDP + ks * 32 + g * 8]);
        o[nt] = __builtin_amdgcn_mfma_f32_16x16x32_bf16(pf[ks], bfrag, o[nt], 0, 0, 0);
      }
  }

  float inv[4];
  #pragma unroll
  for (int r = 0; r < 4; r++) inv[r] = 1.f / l_i[r];
  #pragma unroll
  for (int nt = 0; nt < 8; nt++)
    #pragma unroll
    for (int r = 0; r < 4; r++) {
      size_t row = (size_t)(b * SS + qrow_base + r);
      obuf[row * DD + h * DHH + nt * 16 + l15] = __float2bfloat16(o[nt][r] * inv[r]);
    }
}

// ---------------- LayerNorm(ff) + ReLU -> h (bf16) ----------------
__global__ __launch_bounds__(256) void k_ln1_relu(const bf16* __restrict__ fused,
                                                  const float* __restrict__ gamma,
                                                  const float* __restrict__ beta,
                                                  bf16* __restrict__ h) {
  int row = blockIdx.x;
  const bf16* xr = fused + (size_t)row * NFF + 3 * DD;
  int tid = threadIdx.x;
  float s = 0.f, ss = 0.f;
  for (int i = tid; i < FFF; i += 256) {
    float v = __bfloat162float(xr[i]);
    s += v; ss += v * v;
  }
  #pragma unroll
  for (int off = 32; off > 0; off >>= 1) { s += __shfl_down(s, off); ss += __shfl_down(ss, off); }
  __shared__ float red[8];
  int wave = tid >> 6, lane = tid & 63;
  if (lane == 0) { red[wave] = s; red[4 + wave] = ss; }
  __syncthreads();
  if (tid == 0) {
    float S0 = red[0] + red[1] + red[2] + red[3];
    float SQ = red[4] + red[5] + red[6] + red[7];
    float m = S0 / FFF;
    float var = SQ / FFF - m * m;
    red[0] = m;
    red[1] = 1.f / sqrtf(var + LNEPS);
  }
  __syncthreads();
  float m = red[0], inv = red[1];
  for (int i = tid; i < FFF; i += 256) {
    float v = __bfloat162float(xr[i]);
    float y = gamma[i] * (v - m) * inv + beta[i];
    h[(size_t)row * FFF + i] = __float2bfloat16(fmaxf(y, 0.f));
  }
}

// ---------------- final LayerNorm (f32 in -> f32 out) ----------------
__global__ __launch_bounds__(256) void k_ln2(const float* __restrict__ yin,
                                             const float* __restrict__ gamma,
                                             const float* __restrict__ beta,
                                             float* __restrict__ out) {
  int row = blockIdx.x;
  const float* xr = yin + (size_t)row * DD;
  int tid = threadIdx.x;
  float s = 0.f, ss = 0.f;
  for (int i = tid; i < DD; i += 256) {
    float v = xr[i];
    s += v; ss += v * v;
  }
  #pragma unroll
  for (int off = 32; off > 0; off >>= 1) { s += __shfl_down(s, off); ss += __shfl_down(ss, off); }
  __shared__ float red[8];
  int wave = tid >> 6, lane = tid & 63;
  if (lane == 0) { red[wave] = s; red[4 + wave] = ss; }
  __syncthreads();
  if (tid == 0) {
    float S0 = red[0] + red[1] + red[2] + red[3];
    float SQ = red[4] + red[5] + red[6] + red[7];
    float m = S0 / DD;
    float var = SQ / DD - m * m;
    red[0] = m;
    red[1] = 1.f / sqrtf(var + LNEPS);
  }
  __syncthreads();
  float m = red[0], inv = red[1];
  for (int i = tid; i < DD; i += 256) {
    float v = xr[i];
    out[(size_t)row * DD + i] = gamma[i] * (v - m) * inv + beta[i];
  }
}

extern "C" void kernel_launch(void* const* d_in, const int* in_sizes, int n_in,
                              void* d_out, int out_size, void* d_ws, size_t ws_size,
                              hipStream_t stream) {
  const float* x       = (const float*)d_in[0];
  const float* W_fused = (const float*)d_in[1];
  const float* b_fused = (const float*)d_in[2];
  const float* W_attn  = (const float*)d_in[3];
  const float* b_attn  = (const float*)d_in[4];
  const float* W_ff    = (const float*)d_in[5];
  const float* b_ff    = (const float*)d_in[6];
  const float* gamma1  = (const float*)d_in[7];
  const float* beta1   = (const float*)d_in[8];
  const float* gamma2  = (const float*)d_in[9];
  const float* beta2   = (const float*)d_in[10];
  const float* rope_w  = (const float*)d_in[11];

  char* ws = (char*)d_ws;
  size_t off = 0;
  auto alloc = [&](size_t bytes) -> void* {
    void* p = ws + off;
    off += (bytes + 255) & ~(size_t)255;
    return p;
  };
  bf16* fused = (bf16*)alloc((size_t)MR * NFF * 2);   // 112 MiB
  bf16* xb    = (bf16*)alloc((size_t)MR * DD * 2);    // 16 MiB
  bf16* WfT   = (bf16*)alloc((size_t)NFF * DD * 2);   // 56 MiB
  bf16* WaT   = (bf16*)alloc((size_t)DD * DD * 2);    // 8 MiB
  bf16* WffT  = (bf16*)alloc((size_t)DD * FFF * 2);   // 32 MiB
  bf16* hbuf  = (bf16*)alloc((size_t)MR * FFF * 2);   // 64 MiB
  bf16* obuf  = (bf16*)alloc((size_t)MR * DD * 2);    // 16 MiB
  float* ybuf = (float*)alloc((size_t)MR * DD * 4);   // 32 MiB
  if (off > ws_size) return;  // workspace too small — fail visibly

  // 1. convert x -> bf16
  k_convert<<<(MR * DD / 4 + 255) / 256, 256, 0, stream>>>(x, xb, MR * DD / 4);
  // 2. transpose weights -> bf16 B^T
  k_transpose<<<dim3(NFF / 32, DD / 32), dim3(32, 8), 0, stream>>>(W_fused, WfT, DD, NFF);
  k_transpose<<<dim3(DD / 32, DD / 32), dim3(32, 8), 0, stream>>>(W_attn, WaT, DD, DD);
  k_transpose<<<dim3(DD / 32, FFF / 32), dim3(32, 8), 0, stream>>>(W_ff, WffT, FFF, DD);
  // 3. fused = x @ W_fused + b_fused   (bf16 out)
  k_gemm_bt<<<dim3(NFF / 128, MR / 128), 256, 0, stream>>>(xb, WfT, b_fused, fused, nullptr,
                                                           MR, NFF, DD, 1);
  // 4. RoPE on q,k
  k_rope<<<MR, 256, 0, stream>>>(fused, rope_w);
  // 5. causal flash attention (MFMA) -> obuf (bf16)
  k_flash<<<dim3(SS / 64, BB * HHN), 256, 0, stream>>>(fused, obuf);
  // 6. attn = o @ W_attn + b_attn   (f32 out -> ybuf)
  k_gemm_bt<<<dim3(DD / 128, MR / 128), 256, 0, stream>>>(obuf, WaT, b_attn, ybuf, nullptr,
                                                          MR, DD, DD, 0);
  // 7. h = relu(layernorm(ff))   (bf16)
  k_ln1_relu<<<MR, 256, 0, stream>>>(fused, gamma1, beta1, hbuf);
  // 8. ybuf = attn + silu(h @ W_ff + b_ff)   (in-place add, f32)
  k_gemm_bt<<<dim3(DD / 128, MR / 128), 256, 0, stream>>>(hbuf, WffT, b_ff, ybuf, ybuf,
                                                          MR, DD, FFF, 2);
  // 9. out = layernorm(ybuf)
  k_ln2<<<MR, 256, 0, stream>>>(ybuf, gamma2, beta2, (float*)d_out);
}

// Round 4
// 1176.483 us; speedup vs baseline: 3.0993x; 1.1094x over previous
//
#include <hip/hip_runtime.h>
#include <hip/hip_bf16.h>
#include <cmath>

#define BB 2
#define SS 2048
#define DD 2048
#define HHN 16
#define DHH 128
#define FFF 8192
#define NFF (3*DD+FFF)   // 14336
#define MR (BB*SS)       // 4096
#define LNEPS 1e-6f

typedef __hip_bfloat16 bf16;
using bf16x8 = __attribute__((ext_vector_type(8))) __bf16;
using f32x4  = __attribute__((ext_vector_type(4))) float;

// async global->LDS copy, 16B per lane. HW semantics: LDS dest = wave-uniform
// base + lane*16. Every call site below satisfies: lds_byte_off = uniform + lane*16.
__device__ __forceinline__ void async_copy16(const bf16* g, bf16* l) {
  __builtin_amdgcn_global_load_lds(
      (const __attribute__((address_space(1))) void*)g,
      (__attribute__((address_space(3))) void*)l, 16, 0, 0);
}

// ---------------- convert f32 -> bf16 (vectorized) ----------------
__global__ __launch_bounds__(256) void k_convert(const float* __restrict__ in,
                                                 bf16* __restrict__ out, int n4) {
  int i = blockIdx.x * 256 + threadIdx.x;
  if (i >= n4) return;
  float4 v = ((const float4*)in)[i];
  out[4*i+0] = __float2bfloat16(v.x);
  out[4*i+1] = __float2bfloat16(v.y);
  out[4*i+2] = __float2bfloat16(v.z);
  out[4*i+3] = __float2bfloat16(v.w);
}

// ---------------- transpose+convert: in (R x C) f32 -> out (C x R) bf16 ----------------
__global__ __launch_bounds__(256) void k_transpose(const float* __restrict__ in,
                                                   bf16* __restrict__ out, int R, int C) {
  __shared__ float tile[32][33];
  int c0 = blockIdx.x * 32, r0 = blockIdx.y * 32;
  int tx = threadIdx.x, ty = threadIdx.y;
  #pragma unroll
  for (int i = 0; i < 32; i += 8)
    tile[ty + i][tx] = in[(size_t)(r0 + ty + i) * C + (c0 + tx)];
  __syncthreads();
  #pragma unroll
  for (int i = 0; i < 32; i += 8)
    out[(size_t)(c0 + ty + i) * R + (r0 + tx)] = __float2bfloat16(tile[tx][ty + i]);
}

// ---------------- V pre-transpose: fused v-region -> vT[bh][d][s] (bf16) ----------------
__global__ void k_vtrans(const bf16* __restrict__ fused, bf16* __restrict__ vT) {
  __shared__ bf16 tile[32][33];
  int s0 = blockIdx.x * 32, d0 = blockIdx.y * 32, bh = blockIdx.z;
  int b = bh >> 4, h = bh & 15;
  int tx = threadIdx.x, ty = threadIdx.y;
  const bf16* src = fused + (size_t)(b * SS) * NFF + 2 * DD + h * DHH;
  #pragma unroll
  for (int i = 0; i < 32; i += 8)
    tile[ty + i][tx] = src[(size_t)(s0 + ty + i) * NFF + d0 + tx];
  __syncthreads();
  bf16* dst = vT + ((size_t)bh * DHH) * SS;
  #pragma unroll
  for (int i = 0; i < 32; i += 8)
    dst[(size_t)(d0 + ty + i) * SS + s0 + tx] = tile[tx][ty + i];
}

// ---------------- bf16 MFMA GEMM, 128x128 tile (m97 structure) + panel swizzle ----------
// C[MxN] = A[MxK] @ BT[NxK]^T + bias ; 1-D grid, panels of 16 n-cols x full M
// mode 0: C f32 = v ; mode 1: C bf16 = v ; mode 2: C f32 = addin + silu(v)
__global__ __launch_bounds__(256) void k_gemm_bt(const bf16* __restrict__ A,
                                                 const bf16* __restrict__ BT,
                                                 const float* __restrict__ bias,
                                                 void* __restrict__ Cout,
                                                 const float* __restrict__ addin,
                                                 int M, int N, int K, int mode) {
  __shared__ __align__(16) bf16 As[128 * 32];  // 8 KiB
  __shared__ __align__(16) bf16 Bs[128 * 32];  // 8 KiB
  int NBm = M >> 7;
  constexpr int PW = 16;  // panel width in n-blocks; resident set ~24MB < 32MB agg L2
  int bid = blockIdx.x;
  int pid = bid / (PW * NBm), rem = bid % (PW * NBm);
  int by = rem / PW, bx = pid * PW + rem % PW;
  int tid = threadIdx.x;
  int w = tid >> 6, l = tid & 63;
  int wm = w >> 1, wn = w & 1;
  int l15 = l & 15, g = l >> 4;
  int sr4 = l >> 2, sc4 = (l & 3) * 8;
  int m0 = by * 128, n0 = bx * 128;

  f32x4 acc[4][4];
  #pragma unroll
  for (int i = 0; i < 4; i++)
    #pragma unroll
    for (int j = 0; j < 4; j++)
      acc[i][j] = f32x4{0.f, 0.f, 0.f, 0.f};

  for (int k0 = 0; k0 < K; k0 += 32) {
    __syncthreads();
    #pragma unroll
    for (int i = 0; i < 2; i++) {
      int r = (w * 2 + i) * 16 + sr4;  // 0..127 ; lds off = uniform + l*16B
      async_copy16(A + (size_t)(m0 + r) * K + k0 + sc4, &As[r * 32 + sc4]);
      async_copy16(BT + (size_t)(n0 + r) * K + k0 + sc4, &Bs[r * 32 + sc4]);
    }
    __syncthreads();

    bf16x8 af[4], bf_[4];
    #pragma unroll
    for (int i = 0; i < 4; i++)
      af[i] = *reinterpret_cast<const bf16x8*>(&As[(wm * 64 + i * 16 + l15) * 32 + g * 8]);
    #pragma unroll
    for (int j = 0; j < 4; j++)
      bf_[j] = *reinterpret_cast<const bf16x8*>(&Bs[(wn * 64 + j * 16 + l15) * 32 + g * 8]);
    #pragma unroll
    for (int i = 0; i < 4; i++)
      #pragma unroll
      for (int j = 0; j < 4; j++)
        acc[i][j] = __builtin_amdgcn_mfma_f32_16x16x32_bf16(af[i], bf_[j], acc[i][j], 0, 0, 0);
  }

  float* Cf = (float*)Cout;
  bf16* Cb = (bf16*)Cout;
  #pragma unroll
  for (int i = 0; i < 4; i++) {
    #pragma unroll
    for (int j = 0; j < 4; j++) {
      int mbase = m0 + wm * 64 + i * 16 + g * 4;
      int nn = n0 + wn * 64 + j * 16 + l15;
      float bv = bias[nn];
      #pragma unroll
      for (int rr = 0; rr < 4; rr++) {
        size_t idx = (size_t)(mbase + rr) * N + nn;
        float v = acc[i][j][rr] + bv;
        if (mode == 0) {
          Cf[idx] = v;
        } else if (mode == 1) {
          Cb[idx] = __float2bfloat16(v);
        } else {
          float sig = 1.f / (1.f + expf(-v));
          Cf[idx] = addin[idx] + v * sig;
        }
      }
    }
  }
}

// ---------------- cos/sin table: tab[s*DHH+d] = {cos(rw), sin(rw)} ----------------
__global__ __launch_bounds__(256) void k_sincos(const float* __restrict__ rope_w,
                                                float2* __restrict__ tab) {
  int i = blockIdx.x * 256 + threadIdx.x;
  if (i >= SS * DHH) return;
  float v = rope_w[i];
  tab[i] = make_float2(cosf(v), sinf(v));
}

// ---------------- RoPE in-place on q,k of fused (vectorized, table-driven) ----------------
// ref rotate_half has NO negation: out[d]=x[d]*c[d]+x[d+64]*s[d]; out[d+64]=x[d+64]*c[d+64]+x[d]*s[d+64]
__global__ __launch_bounds__(256) void k_rope(bf16* __restrict__ fused,
                                              const float2* __restrict__ tab) {
  int row = blockIdx.x;
  int s = row & (SS - 1);
  const float2* tr = tab + (size_t)s * DHH;
  int tid = threadIdx.x;
  int isK = tid >> 7, ch = tid & 127;
  int h = ch >> 3, c0 = (ch & 7) * 8;
  const float scale = 0.08838834764831845f;  // 1/sqrt(128); q only
  bf16* base = fused + (size_t)row * NFF + isK * DD + h * DHH;
  bf16x8 lo = *reinterpret_cast<const bf16x8*>(base + c0);
  bf16x8 hi = *reinterpret_cast<const bf16x8*>(base + c0 + 64);
  bf16x8 olo, ohi;
  #pragma unroll
  for (int t = 0; t < 8; t++) {
    int d = c0 + t;
    float2 cl = tr[d], chh = tr[d + 64];
    float x0 = (float)lo[t], x1 = (float)hi[t];
    float r0 = x0 * cl.x + x1 * cl.y;
    float r1 = x1 * chh.x + x0 * chh.y;
    if (!isK) { r0 *= scale; r1 *= scale; }
    olo[t] = (__bf16)r0;
    ohi[t] = (__bf16)r1;
  }
  *reinterpret_cast<bf16x8*>(base + c0) = olo;
  *reinterpret_cast<bf16x8*>(base + c0 + 64) = ohi;
}

// ---------------- causal flash attention, MFMA + async staging ----------------
// grid: (S/64, B*H), 256 threads = 4 waves. Wave w owns q-rows [w*16, w*16+16).
// LDS layouts all [chunk][row][32] unpadded (m97 pattern; async-compatible).
__global__ __launch_bounds__(256) void k_flash(const bf16* __restrict__ fused,
                                               const bf16* __restrict__ vT,
                                               bf16* __restrict__ obuf) {
  __shared__ __align__(16) bf16 smem[20480];  // 40 KiB
  bf16* Ks = smem;          // [4][64][32]  16 KiB  (chunk=ks over d)
  bf16* Vt = smem + 8192;   // [2][128][32] 16 KiB  (chunk=kc over keys, row=d)
  bf16* Ps = smem + 16384;  // [2][64][32]   8 KiB  (chunk over keys, wave-private rows)
  bf16* Qs = smem;          // overlay with Ks (Q frags hoisted before loop)

  int qb = blockIdx.x, bh = blockIdx.y;
  int b = bh >> 4, h = bh & 15;
  int tid = threadIdx.x;
  int w = tid >> 6, l = tid & 63;
  int l15 = l & 15, g = l >> 4;

  const bf16* qbase = fused + (size_t)(b * SS + qb * 64) * NFF + h * DHH;
  const bf16* kbase = fused + (size_t)(b * SS) * NFF + DD + h * DHH;
  const bf16* vtb = vT + (size_t)bh * DHH * SS;

  // ---- stage Q (64 rows x 128 d) async: lds off = ks*4096B + w*1024B + l*16B ----
  #pragma unroll
  for (int ks = 0; ks < 4; ks++)
    async_copy16(qbase + (size_t)(w * 16 + (l >> 2)) * NFF + ks * 32 + (l & 3) * 8,
                 &Qs[ks * 2048 + w * 512 + l * 8]);
  __syncthreads();
  bf16x8 qf[4];
  #pragma unroll
  for (int ks = 0; ks < 4; ks++)
    qf[ks] = *reinterpret_cast<const bf16x8*>(&Qs[ks * 2048 + (w * 16 + l15) * 32 + g * 8]);

  f32x4 o[8];
  #pragma unroll
  for (int nt = 0; nt < 8; nt++) o[nt] = f32x4{0.f, 0.f, 0.f, 0.f};
  float m_i[4], l_i[4];
  #pragma unroll
  for (int r = 0; r < 4; r++) { m_i[r] = -1e30f; l_i[r] = 0.f; }
  int qrow_base = qb * 64 + w * 16 + g * 4;  // + r

  for (int kt = 0; kt <= qb; kt++) {
    __syncthreads();  // all waves done reading Qs/Ks/Vt
    // ---- stage K tile: Ks[ks][key][d'] ; wave w covers keys w*16..+16 ----
    #pragma unroll
    for (int ks = 0; ks < 4; ks++)
      async_copy16(kbase + (size_t)(kt * 64 + w * 16 + (l >> 2)) * NFF + ks * 32 + (l & 3) * 8,
                   &Ks[ks * 2048 + w * 512 + l * 8]);
    // ---- stage V^T tile: Vt[kc][d][key'] from vT[d][s] ----
    #pragma unroll
    for (int j = 0; j < 2; j++)
      #pragma unroll
      for (int kc = 0; kc < 2; kc++)
        async_copy16(vtb + (size_t)(j * 64 + w * 16 + (l >> 2)) * SS + kt * 64 + kc * 32 + (l & 3) * 8,
                     &Vt[kc * 4096 + j * 2048 + w * 512 + l * 8]);
    __syncthreads();  // drains vmcnt

    // ---- S strip = Q_strip (16x128) @ K_tile^T ----
    f32x4 s[4];
    #pragma unroll
    for (int nt = 0; nt < 4; nt++) {
      s[nt] = f32x4{0.f, 0.f, 0.f, 0.f};
      #pragma unroll
      for (int ks = 0; ks < 4; ks++) {
        bf16x8 bfrag = *reinterpret_cast<const bf16x8*>(
            &Ks[ks * 2048 + (nt * 16 + l15) * 32 + g * 8]);
        s[nt] = __builtin_amdgcn_mfma_f32_16x16x32_bf16(qf[ks], bfrag, s[nt], 0, 0, 0);
      }
    }
    // ---- causal mask + online softmax ----
    #pragma unroll
    for (int nt = 0; nt < 4; nt++) {
      int kk = kt * 64 + nt * 16 + l15;
      #pragma unroll
      for (int r = 0; r < 4; r++)
        if (kk > qrow_base + r) s[nt][r] = -1e30f;
    }
    float alpha[4];
    #pragma unroll
    for (int r = 0; r < 4; r++) {
      float mx = fmaxf(fmaxf(s[0][r], s[1][r]), fmaxf(s[2][r], s[3][r]));
      mx = fmaxf(mx, __shfl_xor(mx, 1));
      mx = fmaxf(mx, __shfl_xor(mx, 2));
      mx = fmaxf(mx, __shfl_xor(mx, 4));
      mx = fmaxf(mx, __shfl_xor(mx, 8));
      float mnew = fmaxf(m_i[r], mx);
      alpha[r] = __expf(m_i[r] - mnew);
      m_i[r] = mnew;
      float ls = 0.f;
      #pragma unroll
      for (int nt = 0; nt < 4; nt++) {
        float p = __expf(s[nt][r] - mnew);
        s[nt][r] = p;
        ls += p;
      }
      ls += __shfl_xor(ls, 1);
      ls += __shfl_xor(ls, 2);
      ls += __shfl_xor(ls, 4);
      ls += __shfl_xor(ls, 8);
      l_i[r] = l_i[r] * alpha[r] + ls;
    }
    // ---- P (C-layout) -> Ps (A-layout, bf16); wave-private rows, no barrier ----
    #pragma unroll
    for (int nt = 0; nt < 4; nt++) {
      int kk = nt * 16 + l15;
      #pragma unroll
      for (int r = 0; r < 4; r++)
        *(__bf16*)&Ps[(kk >> 5) * 2048 + (w * 16 + g * 4 + r) * 32 + (kk & 31)] =
            (__bf16)s[nt][r];
    }
    #pragma unroll
    for (int nt = 0; nt < 8; nt++)
      #pragma unroll
      for (int r = 0; r < 4; r++) o[nt][r] *= alpha[r];
    // ---- O_strip += P_strip (16x64) @ V_tile (64x128) ----
    bf16x8 pf[2];
    #pragma unroll
    for (int ks = 0; ks < 2; ks++)
      pf[ks] = *reinterpret_cast<const bf16x8*>(
          &Ps[ks * 2048 + (w * 16 + l15) * 32 + g * 8]);
    #pragma unroll
    for (int nt = 0; nt < 8; nt++)
      #pragma unroll
      for (int ks = 0; ks < 2; ks++) {
        bf16x8 bfrag = *reinterpret_cast<const bf16x8*>(
            &Vt[ks * 4096 + (nt * 16 + l15) * 32 + g * 8]);
        o[nt] = __builtin_amdgcn_mfma_f32_16x16x32_bf16(pf[ks], bfrag, o[nt], 0, 0, 0);
      }
  }

  float inv[4];
  #pragma unroll
  for (int r = 0; r < 4; r++) inv[r] = 1.f / l_i[r];
  #pragma unroll
  for (int nt = 0; nt < 8; nt++)
    #pragma unroll
    for (int r = 0; r < 4; r++) {
      size_t row = (size_t)(b * SS + qrow_base + r);
      obuf[row * DD + h * DHH + nt * 16 + l15] = __float2bfloat16(o[nt][r] * inv[r]);
    }
}

// ---------------- LayerNorm(ff) + ReLU -> h (bf16), single-pass, vectorized ----------------
__global__ __launch_bounds__(256) void k_ln1_relu(const bf16* __restrict__ fused,
                                                  const float* __restrict__ gamma,
                                                  const float* __restrict__ beta,
                                                  bf16* __restrict__ h) {
  int row = blockIdx.x;
  const bf16* xr = fused + (size_t)row * NFF + 3 * DD;
  int tid = threadIdx.x;
  bf16x8 v8[4];
  float s = 0.f, ss = 0.f;
  #pragma unroll
  for (int k = 0; k < 4; k++) {
    v8[k] = *reinterpret_cast<const bf16x8*>(xr + (tid + k * 256) * 8);
    #pragma unroll
    for (int t = 0; t < 8; t++) {
      float v = (float)v8[k][t];
      s += v; ss += v * v;
    }
  }
  #pragma unroll
  for (int off = 32; off > 0; off >>= 1) { s += __shfl_down(s, off); ss += __shfl_down(ss, off); }
  __shared__ float red[8];
  int wave = tid >> 6, lane = tid & 63;
  if (lane == 0) { red[wave] = s; red[4 + wave] = ss; }
  __syncthreads();
  if (tid == 0) {
    float S0 = red[0] + red[1] + red[2] + red[3];
    float SQ = red[4] + red[5] + red[6] + red[7];
    float m = S0 / FFF;
    float var = SQ / FFF - m * m;
    red[0] = m;
    red[1] = 1.f / sqrtf(var + LNEPS);
  }
  __syncthreads();
  float m = red[0], inv = red[1];
  bf16* hr = h + (size_t)row * FFF;
  #pragma unroll
  for (int k = 0; k < 4; k++) {
    bf16x8 o8;
    int base = (tid + k * 256) * 8;
    #pragma unroll
    for (int t = 0; t < 8; t++) {
      float v = (float)v8[k][t];
      float y = gamma[base + t] * (v - m) * inv + beta[base + t];
      o8[t] = (__bf16)fmaxf(y, 0.f);
    }
    *reinterpret_cast<bf16x8*>(hr + base) = o8;
  }
}

// ---------------- final LayerNorm (f32 in -> f32 out), single-pass, vectorized ----------------
__global__ __launch_bounds__(256) void k_ln2(const float* __restrict__ yin,
                                             const float* __restrict__ gamma,
                                             const float* __restrict__ beta,
                                             float* __restrict__ out) {
  int row = blockIdx.x;
  const float4* xr = (const float4*)(yin + (size_t)row * DD);
  int tid = threadIdx.x;
  float4 v4[2];
  float s = 0.f, ss = 0.f;
  #pragma unroll
  for (int k = 0; k < 2; k++) {
    v4[k] = xr[tid + k * 256];
    s += v4[k].x + v4[k].y + v4[k].z + v4[k].w;
    ss += v4[k].x * v4[k].x + v4[k].y * v4[k].y + v4[k].z * v4[k].z + v4[k].w * v4[k].w;
  }
  #pragma unroll
  for (int off = 32; off > 0; off >>= 1) { s += __shfl_down(s, off); ss += __shfl_down(ss, off); }
  __shared__ float red[8];
  int wave = tid >> 6, lane = tid & 63;
  if (lane == 0) { red[wave] = s; red[4 + wave] = ss; }
  __syncthreads();
  if (tid == 0) {
    float S0 = red[0] + red[1] + red[2] + red[3];
    float SQ = red[4] + red[5] + red[6] + red[7];
    float m = S0 / DD;
    float var = SQ / DD - m * m;
    red[0] = m;
    red[1] = 1.f / sqrtf(var + LNEPS);
  }
  __syncthreads();
  float m = red[0], inv = red[1];
  float4* orow = (float4*)(out + (size_t)row * DD);
  #pragma unroll
  for (int k = 0; k < 2; k++) {
    int base = (tid + k * 256) * 4;
    float4 r;
    r.x = gamma[base + 0] * (v4[k].x - m) * inv + beta[base + 0];
    r.y = gamma[base + 1] * (v4[k].y - m) * inv + beta[base + 1];
    r.z = gamma[base + 2] * (v4[k].z - m) * inv + beta[base + 2];
    r.w = gamma[base + 3] * (v4[k].w - m) * inv + beta[base + 3];
    orow[tid + k * 256] = r;
  }
}

extern "C" void kernel_launch(void* const* d_in, const int* in_sizes, int n_in,
                              void* d_out, int out_size, void* d_ws, size_t ws_size,
                              hipStream_t stream) {
  const float* x       = (const float*)d_in[0];
  const float* W_fused = (const float*)d_in[1];
  const float* b_fused = (const float*)d_in[2];
  const float* W_attn  = (const float*)d_in[3];
  const float* b_attn  = (const float*)d_in[4];
  const float* W_ff    = (const float*)d_in[5];
  const float* b_ff    = (const float*)d_in[6];
  const float* gamma1  = (const float*)d_in[7];
  const float* beta1   = (const float*)d_in[8];
  const float* gamma2  = (const float*)d_in[9];
  const float* beta2   = (const float*)d_in[10];
  const float* rope_w  = (const float*)d_in[11];

  char* ws = (char*)d_ws;
  size_t off = 0;
  auto alloc = [&](size_t bytes) -> void* {
    void* p = ws + off;
    off += (bytes + 255) & ~(size_t)255;
    return p;
  };
  bf16* fused = (bf16*)alloc((size_t)MR * NFF * 2);   // 112 MiB
  bf16* xb    = (bf16*)alloc((size_t)MR * DD * 2);    // 16 MiB (dead after fused GEMM)
  bf16* WfT   = (bf16*)alloc((size_t)NFF * DD * 2);   // 56 MiB
  bf16* WaT   = (bf16*)alloc((size_t)DD * DD * 2);    // 8 MiB
  bf16* WffT  = (bf16*)alloc((size_t)DD * FFF * 2);   // 32 MiB
  bf16* hbuf  = (bf16*)alloc((size_t)MR * FFF * 2);   // 64 MiB
  bf16* obuf  = (bf16*)alloc((size_t)MR * DD * 2);    // 16 MiB
  float* ybuf = (float*)alloc((size_t)MR * DD * 4);   // 32 MiB (used from step 6)
  if (off > ws_size) return;
  bf16* vT = xb;               // overlay: V^T [bh][d][s], 16 MiB, live from vtrans..flash
  float2* tab = (float2*)ybuf; // overlay: cos/sin table, 2 MiB, live for rope only

  // 1. convert x -> bf16 ; cos/sin table
  k_convert<<<(MR * DD / 4 + 255) / 256, 256, 0, stream>>>(x, xb, MR * DD / 4);
  k_sincos<<<(SS * DHH + 255) / 256, 256, 0, stream>>>(rope_w, tab);
  // 2. transpose weights -> bf16 B^T
  k_transpose<<<dim3(NFF / 32, DD / 32), dim3(32, 8), 0, stream>>>(W_fused, WfT, DD, NFF);
  k_transpose<<<dim3(DD / 32, DD / 32), dim3(32, 8), 0, stream>>>(W_attn, WaT, DD, DD);
  k_transpose<<<dim3(DD / 32, FFF / 32), dim3(32, 8), 0, stream>>>(W_ff, WffT, FFF, DD);
  // 3. fused = x @ W_fused + b_fused   (bf16 out)
  k_gemm_bt<<<(NFF / 128) * (MR / 128), 256, 0, stream>>>(xb, WfT, b_fused, fused, nullptr,
                                                          MR, NFF, DD, 1);
  // 4. RoPE on q,k (table-driven, vectorized)
  k_rope<<<MR, 256, 0, stream>>>(fused, tab);
  // 5. V^T -> vT (xb now dead), then causal flash attention (MFMA, async staging)
  k_vtrans<<<dim3(SS / 32, DHH / 32, BB * HHN), dim3(32, 8), 0, stream>>>(fused, vT);
  k_flash<<<dim3(SS / 64, BB * HHN), 256, 0, stream>>>(fused, vT, obuf);
  // 6. attn = o @ W_attn + b_attn   (f32 out -> ybuf)
  k_gemm_bt<<<(DD / 128) * (MR / 128), 256, 0, stream>>>(obuf, WaT, b_attn, ybuf, nullptr,
                                                         MR, DD, DD, 0);
  // 7. h = relu(layernorm(ff))   (bf16)
  k_ln1_relu<<<MR, 256, 0, stream>>>(fused, gamma1, beta1, hbuf);
  // 8. ybuf = attn + silu(h @ W_ff + b_ff)   (in-place add, f32)
  k_gemm_bt<<<(DD / 128) * (MR / 128), 256, 0, stream>>>(hbuf, WffT, b_ff, ybuf, ybuf,
                                                         MR, DD, FFF, 2);
  // 9. out = layernorm(ybuf)
  k_ln2<<<MR, 256, 0, stream>>>(ybuf, gamma2, beta2, (float*)d_out);
}